// Round 9
// baseline (104.397 us; speedup 1.0000x reference)
//
#include <hip/hip_runtime.h>
#include <hip/hip_fp16.h>

// B=32768, D=128, L=3, R=64, O=64. fp32 in/out, f16 MFMA compute.
// TB=128, 256 WGs x 512 threads (8 waves: p/kh/sb), M-unroll 4 (each wave
// computes all 128 rows) -> core-chunk LDS reads are READ-ONCE. Core staged
// via r8's proven 2-slot drain-0 ring, but in a per-wave-gathered layout
// [d][sb][kh][kbL][lane][16B] so every ds_read_b128 is lane-contiguous
// (conflict-free, no XOR address math). x read exactly once.
typedef _Float16 f16x8 __attribute__((ext_vector_type(8)));
typedef float f32x16 __attribute__((ext_vector_type(16)));

union H2x4 { f16x8 v; __half2 h2[4]; unsigned u[4]; };
union U1H2 { unsigned u; __half2 h; };

#define TB 128              // batch rows per workgroup (256 WGs = 1/CU)
// LDS layout (bytes)
#define XN0_OFF  0          // xn0 [row<128][256B swz] = 32KB; scr0 at reduce time
#define RING_OFF 32768      // 2 x 16KB core chunk ring; scr1 at reduce time
#define T_OFF    65536      // T buffer [128][64]f16, 128B rows, XOR swz = 16KB
#define XN12_OFF 81920      // xn slices 1,2: [d<128] pitch 520B = 66560B
#define SMEM_BYTES 148480   // 1 WG/CU (<= 163840)
// workspace layout (bytes)
#define WS_CT1   0          // core1 -> [d][sb][kh][kbL][lane][16B] f16, 1MB
#define WS_CT2   1048576    // core2 same
#define WS_L0T   2097152    // layer0^T [r][d] f16, 16KB
#define WS_LASTT 2113536    // last^T [o][r] f16, 8KB

#define WAITBAR0() asm volatile("s_waitcnt vmcnt(0)\n\ts_barrier" ::: "memory")

__device__ __forceinline__ void gload_lds16(const void* g, void* l) {
  __builtin_amdgcn_global_load_lds(
      (const __attribute__((address_space(1))) unsigned int*)g,
      (__attribute__((address_space(3))) unsigned int*)l, 16, 0, 0);
}

// stage one 16KB core chunk (2 d's): 2 loads/thread at 512 threads
__device__ __forceinline__ void issue_chunk16(const unsigned char* g,
                                              unsigned char* l, int tid) {
  gload_lds16(g + tid * 16, l + tid * 16);
  gload_lds16(g + tid * 16 + 8192, l + tid * 16 + 8192);
}

__device__ __forceinline__ unsigned pack_h2(float a, float b) {
  return (unsigned)__half_as_ushort(__float2half(a)) |
         ((unsigned)__half_as_ushort(__float2half(b)) << 16);
}

// 4-way (p x kh) cross-wave reduce, staged non-atomic (r8 scheme):
// scr(kh) = 32KB f32 [128][64] (scr0 = xn0 region, scr1 = ring region),
// p0 writes, p1 adds, p0 combines kh-pair -> T [128][64] f16 swizzled.
__device__ __forceinline__ void reduce_T(unsigned char* smem,
                                         f32x16 a0, f32x16 a1, f32x16 a2, f32x16 a3,
                                         int p, int kh, int h, int scol) {
  float* scr = (float*)(smem + (kh ? RING_OFF : XN0_OFF));
  __syncthreads();
  if (p == 0) {
#pragma unroll
    for (int j = 0; j < 16; ++j) {
      const int r0 = (j & 3) + 8 * (j >> 2) + 4 * h;
      scr[r0 * 64 + scol]        = a0[j];
      scr[(32 + r0) * 64 + scol] = a1[j];
      scr[(64 + r0) * 64 + scol] = a2[j];
      scr[(96 + r0) * 64 + scol] = a3[j];
    }
  }
  __syncthreads();
  if (p == 1) {
#pragma unroll
    for (int j = 0; j < 16; ++j) {
      const int r0 = (j & 3) + 8 * (j >> 2) + 4 * h;
      scr[r0 * 64 + scol]        += a0[j];
      scr[(32 + r0) * 64 + scol] += a1[j];
      scr[(64 + r0) * 64 + scol] += a2[j];
      scr[(96 + r0) * 64 + scol] += a3[j];
    }
  }
  __syncthreads();
  if (p == 0) {  // wave (kh,sb) writes T rows {kh*32+r0, 64+kh*32+r0}
    const float* s0 = (const float*)(smem + XN0_OFF);
    const float* s1 = (const float*)(smem + RING_OFF);
#pragma unroll
    for (int j = 0; j < 16; ++j) {
      const int r0 = (j & 3) + 8 * (j >> 2) + 4 * h;
      int row = kh * 32 + r0;
      float vsum = s0[row * 64 + scol] + s1[row * 64 + scol];
      *(__half*)(smem + T_OFF + row * 128 + ((2 * scol) ^ ((row & 7) << 4))) =
          __float2half(vsum);
      row += 64;
      vsum = s0[row * 64 + scol] + s1[row * 64 + scol];
      *(__half*)(smem + T_OFF + row * 128 + ((2 * scol) ^ ((row & 7) << 4))) =
          __float2half(vsum);
    }
  }
  __syncthreads();
}

// ---- prep: cast weights to f16 in the layouts the main kernel wants ----
__global__ void __launch_bounds__(512) tt_prep(
    const float* __restrict__ layer0, const float* __restrict__ core1,
    const float* __restrict__ core2, const float* __restrict__ last,
    unsigned char* __restrict__ ws) {
  const int tid = blockIdx.x * 512 + threadIdx.x;
  if (tid < 524288) {                       // ct: 2 x 262144 words
    const int which = tid >> 18;
    const int w = tid & 262143;
    const float* core = which ? core2 : core1;
    unsigned char* ct = ws + (which ? WS_CT2 : WS_CT1);
    // dest layout: [d][sb][kh][kbL][lp=l31*2+h][16B]; offset == w*4 (linear)
    const int j   = w & 3;                  // word within 16B chunk
    const int lp  = (w >> 2) & 63;          // l31*2 + h
    const int blk = w >> 8;                 // d*8 + sb*4 + kh*2 + kbL
    const int kbL = blk & 1;
    const int kh  = (blk >> 1) & 1;
    const int sb  = (blk >> 2) & 1;
    const int d   = blk >> 3;
    const int hh  = lp & 1;
    const int l31 = lp >> 1;
    const int s   = sb * 32 + l31;
    const int r0  = kh * 32 + kbL * 16 + hh * 8 + 2 * j;
    const unsigned val = pack_h2(core[r0 * 8192 + d * 64 + s],
                                 core[(r0 + 1) * 8192 + d * 64 + s]);
    *(unsigned*)(ct + (size_t)w * 4) = val;
  } else if (tid < 528384) {                // l0t: 4096 words, [r][d] f16 (256B rows)
    const int w = tid - 524288;
    const int r = w >> 6, j = w & 63, d = 2 * j;
    const unsigned val = pack_h2(layer0[d * 64 + r], layer0[(d + 1) * 64 + r]);
    *(unsigned*)(ws + WS_L0T + r * 256 + 4 * j) = val;
  } else if (tid < 530432) {                // lastT: 2048 words, [o][r] f16 (128B rows)
    const int w = tid - 528384;
    const int o = w >> 5, j = w & 31, r = 2 * j;
    const unsigned val = pack_h2(last[r * 64 + o], last[(r + 1) * 64 + o]);
    *(unsigned*)(ws + WS_LASTT + o * 128 + 4 * j) = val;
  }
}

// KR step for one m-block: af = tp * e, two MFMAs (kbL=0/1)
#define KRSTEP(TPa, TPb, E, ACC)                                              \
  do {                                                                        \
    H2x4 af;                                                                  \
    _Pragma("unroll") for (int q = 0; q < 4; ++q)                             \
        af.h2[q] = __hmul2(TPa.h2[q], (E).h);                                 \
    ACC = __builtin_amdgcn_mfma_f32_32x32x16_f16(af.v, bf0, ACC, 0, 0, 0);    \
    _Pragma("unroll") for (int q = 0; q < 4; ++q)                             \
        af.h2[q] = __hmul2(TPb.h2[q], (E).h);                                 \
    ACC = __builtin_amdgcn_mfma_f32_32x32x16_f16(af.v, bf1, ACC, 0, 0, 0);    \
  } while (0)

// ---- fused main kernel: LN + 4-stage tensor-train chain ----
__global__ void __launch_bounds__(512, 2) tt_fused(
    const float* __restrict__ x, const float* __restrict__ lnw,
    const float* __restrict__ lnb, const unsigned char* __restrict__ ws,
    float* __restrict__ out) {
  __shared__ alignas(16) unsigned char smem[SMEM_BYTES];
  const int tid = threadIdx.x;
  const int wid = tid >> 6;
  const int lane = tid & 63;
  const int l31 = lane & 31;
  const int h = lane >> 5;
  const int p  = wid & 1;           // d-parity within chunk
  const int kh = (wid >> 1) & 1;    // r-half (K-split over r)
  const int sb = (wid >> 2) & 1;    // s-block (32 cols)
  const int bg0 = blockIdx.x * TB;
  const int scol = sb * 32 + l31;   // this lane's B-col
  const int lp16 = (l31 * 2 + h) * 16;
  const int swzA = (l31 & 7) << 4;  // == (row&7)<<4 for rows mb*32+l31

  // ---------- phase 0: LN; xn0 -> [row][256B swz]; xn1,2 -> XN12 (pitch 520) ----------
  {
    float wv[6], bv[6];
#pragma unroll
    for (int k = 0; k < 6; ++k) { wv[k] = lnw[lane + 64 * k]; bv[k] = lnb[lane + 64 * k]; }
#pragma unroll
    for (int rr = 0; rr < 16; ++rr) {
      const int row = wid * 16 + rr;          // 8 waves x 16 = 128 rows
      const float* xrow = x + (size_t)(bg0 + row) * 384;
      float v[6];
#pragma unroll
      for (int k = 0; k < 6; ++k) v[k] = xrow[lane + 64 * k];
      float s = 0.f, ss = 0.f;
#pragma unroll
      for (int k = 0; k < 6; ++k) { s += v[k]; ss += v[k] * v[k]; }
#pragma unroll
      for (int m = 1; m < 64; m <<= 1) { s += __shfl_xor(s, m); ss += __shfl_xor(ss, m); }
      const float mu = s * (1.f / 384.f);
      const float var = ss * (1.f / 384.f) - mu * mu;
      const float rstd = rsqrtf(var + 1e-5f);
#pragma unroll
      for (int k = 0; k < 6; ++k) {
        const int i = lane + 64 * k;          // i = 3*d + sl
        const int d = i / 3;
        const int sl = i - 3 * d;
        const float xv = (v[k] - mu) * rstd * wv[k] + bv[k];
        if (sl == 0) {
          *(__half*)(smem + XN0_OFF + row * 256 + ((2 * d) ^ ((row & 7) << 4))) =
              __float2half(xv);
        } else {
          *(__half*)(smem + XN12_OFF + d * 520 + 4 * row + 2 * (sl - 1)) =
              __float2half(xv);
        }
      }
    }
  }
  __syncthreads();

  f32x16 acc0, acc1, acc2, acc3;  // row blocks 0..31 / 32..63 / 64..95 / 96..127

  // ---------- stage A: T1 = xn0 @ layer0 (K=128, 4-way (p,kh) K-split) ----------
#pragma unroll
  for (int i = 0; i < 16; ++i) { acc0[i] = 0.f; acc1[i] = 0.f; acc2[i] = 0.f; acc3[i] = 0.f; }
  {
    const unsigned char* l0t = ws + WS_L0T;
#pragma unroll
    for (int kbL = 0; kbL < 2; ++kbL) {
      const int cb = (((p << 1) | kh) * 2 + kbL) * 32 + h * 16;
      f16x8 bf = *(const f16x8*)(l0t + scol * 256 + cb);
      f16x8 aA = *(const f16x8*)(smem + XN0_OFF + l31 * 256 + (cb ^ swzA));
      f16x8 aB = *(const f16x8*)(smem + XN0_OFF + (32 + l31) * 256 + (cb ^ swzA));
      f16x8 aC = *(const f16x8*)(smem + XN0_OFF + (64 + l31) * 256 + (cb ^ swzA));
      f16x8 aD = *(const f16x8*)(smem + XN0_OFF + (96 + l31) * 256 + (cb ^ swzA));
      acc0 = __builtin_amdgcn_mfma_f32_32x32x16_f16(aA, bf, acc0, 0, 0, 0);
      acc1 = __builtin_amdgcn_mfma_f32_32x32x16_f16(aB, bf, acc1, 0, 0, 0);
      acc2 = __builtin_amdgcn_mfma_f32_32x32x16_f16(aC, bf, acc2, 0, 0, 0);
      acc3 = __builtin_amdgcn_mfma_f32_32x32x16_f16(aD, bf, acc3, 0, 0, 0);
    }
  }
  reduce_T(smem, acc0, acc1, acc2, acc3, p, kh, h, scol);  // -> T1

  // ---------- stages B,C: T = KR(T, xn_l) @ core_l ----------
  for (int st = 0; st < 2; ++st) {
    const unsigned char* ctg = ws + (st ? WS_CT2 : WS_CT1);

    // prologue: chunk 0 -> ring slot 0 (scr regions dead after reduce_T sync)
    issue_chunk16(ctg, smem + RING_OFF, tid);

    // T rows (4 m-blocks x this wave's r-half K=32) into NAMED packed regs
    H2x4 tp00, tp01, tp10, tp11, tp20, tp21, tp30, tp31;   // tp<mb><kbL>
    {
      const int rb0 = kh * 64 + h * 16;
      tp00.v = *(const f16x8*)(smem + T_OFF + l31 * 128 + (rb0 ^ swzA));
      tp01.v = *(const f16x8*)(smem + T_OFF + l31 * 128 + ((rb0 + 32) ^ swzA));
      tp10.v = *(const f16x8*)(smem + T_OFF + (32 + l31) * 128 + (rb0 ^ swzA));
      tp11.v = *(const f16x8*)(smem + T_OFF + (32 + l31) * 128 + ((rb0 + 32) ^ swzA));
      tp20.v = *(const f16x8*)(smem + T_OFF + (64 + l31) * 128 + (rb0 ^ swzA));
      tp21.v = *(const f16x8*)(smem + T_OFF + (64 + l31) * 128 + ((rb0 + 32) ^ swzA));
      tp30.v = *(const f16x8*)(smem + T_OFF + (96 + l31) * 128 + (rb0 ^ swzA));
      tp31.v = *(const f16x8*)(smem + T_OFF + (96 + l31) * 128 + ((rb0 + 32) ^ swzA));
    }

#pragma unroll
    for (int i = 0; i < 16; ++i) { acc0[i] = 0.f; acc1[i] = 0.f; acc2[i] = 0.f; acc3[i] = 0.f; }

    // ring: chunk cg in slot (cg&1); issue cg+1 into the other slot
#pragma unroll 1
    for (int cg = 0; cg < 64; ++cg) {
      WAITBAR0();   // chunk cg landed (issued >= 1 full iteration ago)
      if (cg < 63)
        issue_chunk16(ctg + (cg + 1) * 16384,
                      smem + RING_OFF + ((cg + 1) & 1) * 16384, tid);
      // compute chunk cg: this wave's d = 2*cg + p; fragments lane-contiguous
      const unsigned char* bp = smem + RING_OFF + (cg & 1) * 16384 +
                                p * 8192 + sb * 4096 + kh * 2048 + lp16;
      f16x8 bf0 = *(const f16x8*)(bp);
      f16x8 bf1 = *(const f16x8*)(bp + 1024);
      const unsigned char* xp = smem + XN12_OFF + (2 * cg + p) * 520 +
                                4 * l31 + 2 * st;
      const unsigned xv0 = *(const unsigned short*)(xp);
      const unsigned xv1 = *(const unsigned short*)(xp + 128);
      const unsigned xv2 = *(const unsigned short*)(xp + 256);
      const unsigned xv3 = *(const unsigned short*)(xp + 384);
      U1H2 e0, e1, e2, e3;
      e0.u = xv0 | (xv0 << 16);
      e1.u = xv1 | (xv1 << 16);
      e2.u = xv2 | (xv2 << 16);
      e3.u = xv3 | (xv3 << 16);
      KRSTEP(tp00, tp01, e0, acc0);
      KRSTEP(tp10, tp11, e1, acc1);
      KRSTEP(tp20, tp21, e2, acc2);
      KRSTEP(tp30, tp31, e3, acc3);
    }
    reduce_T(smem, acc0, acc1, acc2, acc3, p, kh, h, scol);  // -> T2 then T3
  }

  // ---------- stage D: out = T3 @ last (p==0 waves; row pairs kh*32, 64+kh*32) ----------
  if (p == 0) {
    f32x16 accd0, accd1;
#pragma unroll
    for (int i = 0; i < 16; ++i) { accd0[i] = 0.f; accd1[i] = 0.f; }
    const unsigned char* lastT = ws + WS_LASTT;
#pragma unroll
    for (int kb = 0; kb < 4; ++kb) {
      const int cb = kb * 32 + h * 16;
      f16x8 bf = *(const f16x8*)(lastT + scol * 128 + cb);
      f16x8 af0 = *(const f16x8*)(smem + T_OFF + (kh * 32 + l31) * 128 + (cb ^ swzA));
      f16x8 af1 = *(const f16x8*)(smem + T_OFF + (64 + kh * 32 + l31) * 128 + (cb ^ swzA));
      accd0 = __builtin_amdgcn_mfma_f32_32x32x16_f16(af0, bf, accd0, 0, 0, 0);
      accd1 = __builtin_amdgcn_mfma_f32_32x32x16_f16(af1, bf, accd1, 0, 0, 0);
    }
#pragma unroll
    for (int j = 0; j < 16; ++j) {
      const int r0 = (j & 3) + 8 * (j >> 2) + 4 * h;
      out[(size_t)(bg0 + kh * 32 + r0) * 64 + scol] = accd0[j];
      out[(size_t)(bg0 + 64 + kh * 32 + r0) * 64 + scol] = accd1[j];
    }
  }
}

extern "C" void kernel_launch(void* const* d_in, const int* in_sizes, int n_in,
                              void* d_out, int out_size, void* d_ws, size_t ws_size,
                              hipStream_t stream) {
  const float* x      = (const float*)d_in[0];
  const float* layer0 = (const float*)d_in[1];
  const float* core1  = (const float*)d_in[2];
  const float* core2  = (const float*)d_in[3];
  const float* last   = (const float*)d_in[4];
  const float* lnw    = (const float*)d_in[5];
  const float* lnb    = (const float*)d_in[6];
  unsigned char* ws   = (unsigned char*)d_ws;
  float* outp         = (float*)d_out;

  tt_prep<<<1036, 512, 0, stream>>>(layer0, core1, core2, last, ws);
  tt_fused<<<256, 512, 0, stream>>>(x, lnw, lnb, ws, outp);
}